// Round 3
// baseline (755.263 us; speedup 1.0000x reference)
//
#include <hip/hip_runtime.h>
#include <hip/hip_bf16.h>
#include <cstddef>
#include <cstdint>

#define N_NODES 100000
#define N_EDGES 800000
#define EPS 1e-5f

typedef __attribute__((ext_vector_type(8))) short bf16x8;
typedef __attribute__((ext_vector_type(4))) float f32x4;
typedef __attribute__((ext_vector_type(8))) unsigned short u16x8;

#define MFMA16(a, b, c) __builtin_amdgcn_mfma_f32_16x16x32_bf16(a, b, c, 0, 0, 0)

__device__ __forceinline__ unsigned short f2bf(float f) {
  return __builtin_bit_cast(unsigned short, __float2bfloat16(f));
}
__device__ __forceinline__ float bf2f(unsigned short u) {
  return __bfloat162float(__builtin_bit_cast(__hip_bfloat16, u));
}

// Load 8 consecutive fp32, convert to one bf16x8 fragment.
__device__ __forceinline__ bf16x8 cvt8(const float* __restrict__ p) {
  float4 u = *(const float4*)p;
  float4 v = *(const float4*)(p + 4);
  bf16x8 r;
  r[0] = (short)f2bf(u.x); r[1] = (short)f2bf(u.y);
  r[2] = (short)f2bf(u.z); r[3] = (short)f2bf(u.w);
  r[4] = (short)f2bf(v.x); r[5] = (short)f2bf(v.y);
  r[6] = (short)f2bf(v.z); r[7] = (short)f2bf(v.w);
  return r;
}

// ---------------------------------------------------------------------------
// Prep: transpose weights to bf16 Wt[n][k].
// Layout in wt: Wt1a[64][128] | Wt2a[64][64] | Wt1b[64][128] | Wt2b[64][64]
// ---------------------------------------------------------------------------
__global__ void prep_w(const float* __restrict__ W1a, const float* __restrict__ W2a,
                       const float* __restrict__ W1b, const float* __restrict__ W2b,
                       unsigned short* __restrict__ wt) {
  int i = blockIdx.x * 256 + threadIdx.x;
  if (i >= 24576) return;
  if (i < 8192) {
    int n = i >> 7, k = i & 127;
    wt[i] = f2bf(W1a[k * 64 + n]);
  } else if (i < 12288) {
    int j = i - 8192; int n = j >> 6, k = j & 63;
    wt[i] = f2bf(W2a[k * 64 + n]);
  } else if (i < 20480) {
    int j = i - 12288; int n = j >> 7, k = j & 127;
    wt[i] = f2bf(W1b[k * 64 + n]);
  } else {
    int j = i - 20480; int n = j >> 6, k = j & 63;
    wt[i] = f2bf(W2b[k * 64 + n]);
  }
}

// ---------------------------------------------------------------------------
// Counting sort of edges by destination node: count -> scan -> rank.
// ---------------------------------------------------------------------------
__global__ void count_edges_i(const int* __restrict__ ei_col, int* __restrict__ cnti) {
  int e = blockIdx.x * 256 + threadIdx.x;
  if (e < N_EDGES) atomicAdd(&cnti[ei_col[e]], 1);
}

#define SCAN_T 1024
__global__ void scan_offsets(const int* __restrict__ cnti, int* __restrict__ off,
                             int* __restrict__ cursor) {
  __shared__ int part[SCAN_T];
  int t = threadIdx.x;
  const int chunk = (N_NODES + SCAN_T - 1) / SCAN_T;  // 98
  int lo = t * chunk;
  int hi = lo + chunk; if (hi > N_NODES) hi = N_NODES;
  int s = 0;
  for (int i = lo; i < hi; i++) s += cnti[i];
  part[t] = s;
  __syncthreads();
  if (t == 0) {
    int run = 0;
    for (int i = 0; i < SCAN_T; i++) { int v = part[i]; part[i] = run; run += v; }
  }
  __syncthreads();
  int run = part[t];
  for (int i = lo; i < hi; i++) {
    off[i] = run; cursor[i] = run;
    run += cnti[i];
  }
}

// rank[e] = position of edge e in dest-sorted order.
__global__ void rank_edges(const int* __restrict__ ei_col, int* __restrict__ cursor,
                           int* __restrict__ rank) {
  int e = blockIdx.x * 256 + threadIdx.x;
  if (e < N_EDGES) {
    int c = ei_col[e];
    rank[e] = atomicAdd(&cursor[c], 1);
  }
}

// ---------------------------------------------------------------------------
// BN finalize: reduce 64 partial slots -> scale/shift per column.
// ---------------------------------------------------------------------------
__global__ void bn_finalize(const float* __restrict__ st, const float* __restrict__ g,
                            const float* __restrict__ be, float* __restrict__ scsh,
                            float inv_count) {
  int j = threadIdx.x;
  float s = 0.f, q = 0.f;
  for (int k = 0; k < 64; k++) { s += st[k * 128 + j]; q += st[k * 128 + 64 + j]; }
  float mu = s * inv_count;
  float var = q * inv_count - mu * mu;
  float sc = g[j] * rsqrtf(var + EPS);
  scsh[j] = sc;
  scsh[64 + j] = be[j] - mu * sc;
}

// ---------------------------------------------------------------------------
// Edge MLP layer 1 (K=128). Direct global->reg A-fragments, W via LDS.
// Output rows written at rank[e] (dest-sorted), so the aggregation pass
// streams. Fused BN-stat accumulation.
// ---------------------------------------------------------------------------
__global__ __launch_bounds__(256, 4)
void edge_mlp1_mfma(const float* __restrict__ x, const int* __restrict__ ei_row,
                    const float* __restrict__ ea, const int* __restrict__ rank,
                    const unsigned short* __restrict__ Wt,
                    const float* __restrict__ b1,
                    unsigned short* __restrict__ h1, float* __restrict__ stats) {
  __shared__ unsigned short Wl[64 * 136];
  __shared__ int rows[128];
  __shared__ int rankl[128];
  int tid = threadIdx.x;
  int base = blockIdx.x * 128;
  if (tid < 128) {
    rows[tid] = ei_row[base + tid];
    rankl[tid] = rank[base + tid];
  }
#pragma unroll
  for (int i = 0; i < 4; i++) {
    int g = i * 256 + tid;
    int n = g >> 4, k0 = (g & 15) * 8;
    *(u16x8*)&Wl[n * 136 + k0] = *(const u16x8*)&Wt[n * 128 + k0];
  }
  __syncthreads();

  int l = tid & 63, w = tid >> 6;
  int m16 = l & 15, g4 = l >> 4;
  int er0 = w * 32 + m16, er1 = er0 + 16;

  const float* xp0 = &x[(size_t)rows[er0] * 64 + g4 * 8];
  const float* xp1 = &x[(size_t)rows[er1] * 64 + g4 * 8];
  const float* ep0 = &ea[(size_t)(base + er0) * 64 + g4 * 8];
  const float* ep1 = &ea[(size_t)(base + er1) * 64 + g4 * 8];

  bf16x8 a[2][4];
  a[0][0] = cvt8(xp0);      a[0][1] = cvt8(xp0 + 32);
  a[1][0] = cvt8(xp1);      a[1][1] = cvt8(xp1 + 32);
  a[0][2] = cvt8(ep0);      a[0][3] = cvt8(ep0 + 32);
  a[1][2] = cvt8(ep1);      a[1][3] = cvt8(ep1 + 32);

  f32x4 acc[2][4];
#pragma unroll
  for (int nt = 0; nt < 4; nt++) {
    float bv = b1[nt * 16 + m16];
#pragma unroll
    for (int mt = 0; mt < 2; mt++) acc[mt][nt] = (f32x4){bv, bv, bv, bv};
  }
#pragma unroll
  for (int kit = 0; kit < 4; kit++) {
    bf16x8 b[4];
#pragma unroll
    for (int nt = 0; nt < 4; nt++)
      b[nt] = *(const bf16x8*)&Wl[(nt * 16 + m16) * 136 + kit * 32 + g4 * 8];
#pragma unroll
    for (int mt = 0; mt < 2; mt++)
#pragma unroll
      for (int nt = 0; nt < 4; nt++)
        acc[mt][nt] = MFMA16(a[mt][kit], b[nt], acc[mt][nt]);
  }

  float ps[4] = {0, 0, 0, 0}, pq[4] = {0, 0, 0, 0};
#pragma unroll
  for (int mt = 0; mt < 2; mt++) {
#pragma unroll
    for (int r = 0; r < 4; r++) {
      int prow = rankl[w * 32 + mt * 16 + g4 * 4 + r];
#pragma unroll
      for (int nt = 0; nt < 4; nt++) {
        float v = acc[mt][nt][r];
        h1[(size_t)prow * 64 + nt * 16 + m16] = f2bf(v);
        ps[nt] += v; pq[nt] += v * v;
      }
    }
  }
#pragma unroll
  for (int nt = 0; nt < 4; nt++) {
    ps[nt] += __shfl_xor(ps[nt], 16); ps[nt] += __shfl_xor(ps[nt], 32);
    pq[nt] += __shfl_xor(pq[nt], 16); pq[nt] += __shfl_xor(pq[nt], 32);
  }
  float ssel = (g4 == 0) ? ps[0] : (g4 == 1) ? ps[1] : (g4 == 2) ? ps[2] : ps[3];
  float qsel = (g4 == 0) ? pq[0] : (g4 == 1) ? pq[1] : (g4 == 2) ? pq[2] : pq[3];
  int slot = blockIdx.x & 63;
  atomicAdd(&stats[slot * 128 + l], ssel);
  atomicAdd(&stats[slot * 128 + 64 + l], qsel);
}

// ---------------------------------------------------------------------------
// CSR segmented mean of relu(bn(h1)) per node. h1 is dest-sorted, so each
// node's rows are contiguous: pure streaming reads, no atomics.
// One wave per node, lane = channel. Output bf16.
// ---------------------------------------------------------------------------
__global__ __launch_bounds__(256)
void gather_g(const unsigned short* __restrict__ h1, const int* __restrict__ off,
              const int* __restrict__ cnti, const float* __restrict__ scsh,
              unsigned short* __restrict__ g) {
  int w = threadIdx.x >> 6, l = threadIdx.x & 63;
  int n = blockIdx.x * 4 + w;
  if (n >= N_NODES) return;
  float sc = scsh[l], sh = scsh[64 + l];
  int o = off[n], d = cnti[n];
  float s = 0.f;
  int i = 0;
  for (; i + 2 <= d; i += 2) {
    float v0 = bf2f(h1[(size_t)(o + i) * 64 + l]);
    float v1 = bf2f(h1[(size_t)(o + i + 1) * 64 + l]);
    s += fmaxf(fmaf(v0, sc, sh), 0.f);
    s += fmaxf(fmaf(v1, sc, sh), 0.f);
  }
  if (i < d) {
    float v0 = bf2f(h1[(size_t)(o + i) * 64 + l]);
    s += fmaxf(fmaf(v0, sc, sh), 0.f);
  }
  float inv = (d > 0) ? (1.f / (float)d) : 1.f;
  g[(size_t)n * 64 + l] = f2bf(s * inv);
}

// ---------------------------------------------------------------------------
// Node-level second edge-MLP layer: m = g @ W2a + b2a for cnt>0, else 0.
// (Linearity: mean(relu @ W2a + b2a) = mean(relu) @ W2a + b2a when cnt>0;
//  reference gives exactly 0 for empty segments.) 100k rows instead of 800k.
// ---------------------------------------------------------------------------
__global__ __launch_bounds__(256, 4)
void node_agg_mfma(const unsigned short* __restrict__ g, const int* __restrict__ cnti,
                   const unsigned short* __restrict__ Wt2, const float* __restrict__ b2,
                   unsigned short* __restrict__ m) {
  __shared__ unsigned short Wl[64 * 72];
  int tid = threadIdx.x;
  int base = blockIdx.x * 128;
#pragma unroll
  for (int i = 0; i < 2; i++) {
    int gg = i * 256 + tid;
    int n = gg >> 3, k0 = (gg & 7) * 8;
    *(u16x8*)&Wl[n * 72 + k0] = *(const u16x8*)&Wt2[n * 64 + k0];
  }
  __syncthreads();

  int l = tid & 63, w = tid >> 6;
  int m16 = l & 15, g4 = l >> 4;
  int r0 = base + w * 32 + m16, r1 = r0 + 16;
  int c0 = (r0 < N_NODES) ? r0 : 0;
  int c1 = (r1 < N_NODES) ? r1 : 0;

  bf16x8 a[2][2];
  a[0][0] = *(const bf16x8*)&g[(size_t)c0 * 64 + g4 * 8];
  a[0][1] = *(const bf16x8*)&g[(size_t)c0 * 64 + 32 + g4 * 8];
  a[1][0] = *(const bf16x8*)&g[(size_t)c1 * 64 + g4 * 8];
  a[1][1] = *(const bf16x8*)&g[(size_t)c1 * 64 + 32 + g4 * 8];

  f32x4 acc[2][4];
#pragma unroll
  for (int nt = 0; nt < 4; nt++) {
    float bv = b2[nt * 16 + m16];
#pragma unroll
    for (int mt = 0; mt < 2; mt++) acc[mt][nt] = (f32x4){bv, bv, bv, bv};
  }
#pragma unroll
  for (int kit = 0; kit < 2; kit++) {
    bf16x8 b[4];
#pragma unroll
    for (int nt = 0; nt < 4; nt++)
      b[nt] = *(const bf16x8*)&Wl[(nt * 16 + m16) * 72 + kit * 32 + g4 * 8];
#pragma unroll
    for (int mt = 0; mt < 2; mt++)
#pragma unroll
      for (int nt = 0; nt < 4; nt++)
        acc[mt][nt] = MFMA16(a[mt][kit], b[nt], acc[mt][nt]);
  }
#pragma unroll
  for (int mt = 0; mt < 2; mt++) {
#pragma unroll
    for (int r = 0; r < 4; r++) {
      int row = base + w * 32 + mt * 16 + g4 * 4 + r;
      if (row < N_NODES) {
        bool nz = cnti[row] > 0;
#pragma unroll
        for (int nt = 0; nt < 4; nt++) {
          m[(size_t)row * 64 + nt * 16 + m16] = nz ? f2bf(acc[mt][nt][r]) : (unsigned short)0;
        }
      }
    }
  }
}

// ---------------------------------------------------------------------------
// Node MLP layer 1 (K=128): A = concat(x[n] (f32->bf16), m[n] (bf16)).
// Original W1b/b1b. Fused BN-stat accumulation.
// ---------------------------------------------------------------------------
__global__ __launch_bounds__(256, 4)
void node_mlp1_mfma(const float* __restrict__ x, const unsigned short* __restrict__ m,
                    const unsigned short* __restrict__ Wt,
                    const float* __restrict__ b1,
                    unsigned short* __restrict__ h2, float* __restrict__ stats) {
  __shared__ unsigned short Wl[64 * 136];
  int tid = threadIdx.x;
  int base = blockIdx.x * 128;
#pragma unroll
  for (int i = 0; i < 4; i++) {
    int g = i * 256 + tid;
    int n = g >> 4, k0 = (g & 15) * 8;
    *(u16x8*)&Wl[n * 136 + k0] = *(const u16x8*)&Wt[n * 128 + k0];
  }
  __syncthreads();

  int l = tid & 63, w = tid >> 6;
  int m16 = l & 15, g4 = l >> 4;
  int r0 = base + w * 32 + m16, r1 = r0 + 16;
  int c0 = (r0 < N_NODES) ? r0 : 0;
  int c1 = (r1 < N_NODES) ? r1 : 0;

  const float* xp0 = &x[(size_t)c0 * 64 + g4 * 8];
  const float* xp1 = &x[(size_t)c1 * 64 + g4 * 8];

  bf16x8 a[2][4];
  a[0][0] = cvt8(xp0);      a[0][1] = cvt8(xp0 + 32);
  a[1][0] = cvt8(xp1);      a[1][1] = cvt8(xp1 + 32);
  a[0][2] = *(const bf16x8*)&m[(size_t)c0 * 64 + g4 * 8];
  a[0][3] = *(const bf16x8*)&m[(size_t)c0 * 64 + 32 + g4 * 8];
  a[1][2] = *(const bf16x8*)&m[(size_t)c1 * 64 + g4 * 8];
  a[1][3] = *(const bf16x8*)&m[(size_t)c1 * 64 + 32 + g4 * 8];

  f32x4 acc[2][4];
#pragma unroll
  for (int nt = 0; nt < 4; nt++) {
    float bv = b1[nt * 16 + m16];
#pragma unroll
    for (int mt = 0; mt < 2; mt++) acc[mt][nt] = (f32x4){bv, bv, bv, bv};
  }
#pragma unroll
  for (int kit = 0; kit < 4; kit++) {
    bf16x8 b[4];
#pragma unroll
    for (int nt = 0; nt < 4; nt++)
      b[nt] = *(const bf16x8*)&Wl[(nt * 16 + m16) * 136 + kit * 32 + g4 * 8];
#pragma unroll
    for (int mt = 0; mt < 2; mt++)
#pragma unroll
      for (int nt = 0; nt < 4; nt++)
        acc[mt][nt] = MFMA16(a[mt][kit], b[nt], acc[mt][nt]);
  }

  float ps[4] = {0, 0, 0, 0}, pq[4] = {0, 0, 0, 0};
#pragma unroll
  for (int mt = 0; mt < 2; mt++) {
    int nrow = base + w * 32 + mt * 16 + g4 * 4;
#pragma unroll
    for (int nt = 0; nt < 4; nt++) {
      int ch = nt * 16 + m16;
#pragma unroll
      for (int r = 0; r < 4; r++) {
        float v = acc[mt][nt][r];
        if (nrow + r < N_NODES) {
          h2[(size_t)(nrow + r) * 64 + ch] = f2bf(v);
          ps[nt] += v; pq[nt] += v * v;
        }
      }
    }
  }
#pragma unroll
  for (int nt = 0; nt < 4; nt++) {
    ps[nt] += __shfl_xor(ps[nt], 16); ps[nt] += __shfl_xor(ps[nt], 32);
    pq[nt] += __shfl_xor(pq[nt], 16); pq[nt] += __shfl_xor(pq[nt], 32);
  }
  float ssel = (g4 == 0) ? ps[0] : (g4 == 1) ? ps[1] : (g4 == 2) ? ps[2] : ps[3];
  float qsel = (g4 == 0) ? pq[0] : (g4 == 1) ? pq[1] : (g4 == 2) ? pq[2] : pq[3];
  int slot = blockIdx.x & 63;
  atomicAdd(&stats[slot * 128 + l], ssel);
  atomicAdd(&stats[slot * 128 + 64 + l], qsel);
}

// ---------------------------------------------------------------------------
// Node MLP layer 2 (K=64): BN+ReLU in registers; direct store. Guards.
// ---------------------------------------------------------------------------
__global__ __launch_bounds__(256, 4)
void node_mlp2_mfma(const unsigned short* __restrict__ h2, const unsigned short* __restrict__ Wt2,
                    const float* __restrict__ b2, const float* __restrict__ scsh,
                    float* __restrict__ out) {
  __shared__ unsigned short Wl[64 * 72];
  int tid = threadIdx.x;
  int base = blockIdx.x * 128;
#pragma unroll
  for (int i = 0; i < 2; i++) {
    int g = i * 256 + tid;
    int n = g >> 3, k0 = (g & 7) * 8;
    *(u16x8*)&Wl[n * 72 + k0] = *(const u16x8*)&Wt2[n * 64 + k0];
  }
  __syncthreads();

  int l = tid & 63, w = tid >> 6;
  int m16 = l & 15, g4 = l >> 4;
  int r0 = base + w * 32 + m16, r1 = r0 + 16;
  int c0 = (r0 < N_NODES) ? r0 : 0;
  int c1 = (r1 < N_NODES) ? r1 : 0;

  float sc[2][8], sh[2][8];
#pragma unroll
  for (int kit = 0; kit < 2; kit++) {
    int k = kit * 32 + g4 * 8;
    float4 s0 = *(const float4*)&scsh[k];
    float4 s1 = *(const float4*)&scsh[k + 4];
    float4 t0 = *(const float4*)&scsh[64 + k];
    float4 t1 = *(const float4*)&scsh[64 + k + 4];
    sc[kit][0] = s0.x; sc[kit][1] = s0.y; sc[kit][2] = s0.z; sc[kit][3] = s0.w;
    sc[kit][4] = s1.x; sc[kit][5] = s1.y; sc[kit][6] = s1.z; sc[kit][7] = s1.w;
    sh[kit][0] = t0.x; sh[kit][1] = t0.y; sh[kit][2] = t0.z; sh[kit][3] = t0.w;
    sh[kit][4] = t1.x; sh[kit][5] = t1.y; sh[kit][6] = t1.z; sh[kit][7] = t1.w;
  }

  bf16x8 a[2][2];
#pragma unroll
  for (int mt = 0; mt < 2; mt++) {
    const unsigned short* hp = &h2[(size_t)(mt ? c1 : c0) * 64 + g4 * 8];
#pragma unroll
    for (int kit = 0; kit < 2; kit++) {
      u16x8 hv = *(const u16x8*)(hp + kit * 32);
      bf16x8 o;
#pragma unroll
      for (int j = 0; j < 8; j++) {
        float v = fmaxf(fmaf(bf2f(hv[j]), sc[kit][j], sh[kit][j]), 0.f);
        o[j] = (short)f2bf(v);
      }
      a[mt][kit] = o;
    }
  }

  f32x4 acc[2][4];
#pragma unroll
  for (int nt = 0; nt < 4; nt++) {
    float bv = b2[nt * 16 + m16];
#pragma unroll
    for (int mt = 0; mt < 2; mt++) acc[mt][nt] = (f32x4){bv, bv, bv, bv};
  }
#pragma unroll
  for (int kit = 0; kit < 2; kit++) {
    bf16x8 b[4];
#pragma unroll
    for (int nt = 0; nt < 4; nt++)
      b[nt] = *(const bf16x8*)&Wl[(nt * 16 + m16) * 72 + kit * 32 + g4 * 8];
#pragma unroll
    for (int mt = 0; mt < 2; mt++)
#pragma unroll
      for (int nt = 0; nt < 4; nt++)
        acc[mt][nt] = MFMA16(a[mt][kit], b[nt], acc[mt][nt]);
  }
#pragma unroll
  for (int mt = 0; mt < 2; mt++) {
    int nrow = base + w * 32 + mt * 16 + g4 * 4;
#pragma unroll
    for (int nt = 0; nt < 4; nt++) {
      int ch = nt * 16 + m16;
#pragma unroll
      for (int r = 0; r < 4; r++) {
        if (nrow + r < N_NODES) out[(size_t)(nrow + r) * 64 + ch] = acc[mt][nt][r];
      }
    }
  }
}

// ---------------------------------------------------------------------------
extern "C" void kernel_launch(void* const* d_in, const int* in_sizes, int n_in,
                              void* d_out, int out_size, void* d_ws, size_t ws_size,
                              hipStream_t stream) {
  const float* x   = (const float*)d_in[0];
  const int*   ei  = (const int*)d_in[1];   // [2,E]: rows then cols
  const float* ea  = (const float*)d_in[2];
  const float* W1a = (const float*)d_in[5];
  const float* b1a = (const float*)d_in[6];
  const float* g1  = (const float*)d_in[7];
  const float* be1 = (const float*)d_in[8];
  const float* W2a = (const float*)d_in[9];
  const float* b2a = (const float*)d_in[10];
  const float* W1b = (const float*)d_in[11];
  const float* b1b = (const float*)d_in[12];
  const float* g2  = (const float*)d_in[13];
  const float* be2 = (const float*)d_in[14];
  const float* W2b = (const float*)d_in[15];
  const float* b2b = (const float*)d_in[16];
  float* out = (float*)d_out;

  // Workspace layout
  char* p = (char*)d_ws;
  unsigned short* h1 = (unsigned short*)p;  p += (size_t)N_EDGES * 64 * 2;  // 102.4 MB
  unsigned short* gb = (unsigned short*)p;  p += (size_t)N_NODES * 64 * 2;  // 12.8 MB
  unsigned short* mb = (unsigned short*)p;  p += (size_t)N_NODES * 64 * 2;  // 12.8 MB
  // --- zeroed region start ---
  int* cnti = (int*)p;                      p += (size_t)N_NODES * 4;       // 0.4 MB
  float* stats1 = (float*)p;                p += 8192 * 4;
  float* stats2 = (float*)p;                p += 8192 * 4;
  // --- zeroed region end ---
  int* off = (int*)p;                       p += (size_t)N_NODES * 4;
  int* cursor = (int*)p;                    p += (size_t)N_NODES * 4;
  int* rank = (int*)p;                      p += (size_t)N_EDGES * 4;       // 3.2 MB
  float* scsh1 = (float*)p;                 p += 128 * 4;
  float* scsh2 = (float*)p;                 p += 128 * 4;
  unsigned short* h2 = (unsigned short*)p;  p += (size_t)N_NODES * 64 * 2;  // 12.8 MB
  unsigned short* wt = (unsigned short*)p;  // 24576 bf16
  unsigned short* wt1a = wt;
  unsigned short* wt2a = wt + 8192;
  unsigned short* wt1b = wt + 12288;
  unsigned short* wt2b = wt + 20480;

  size_t zbytes = (size_t)N_NODES * 4 + 2 * 8192 * 4;
  (void)hipMemsetAsync(cnti, 0, zbytes, stream);

  prep_w<<<96, 256, 0, stream>>>(W1a, W2a, W1b, W2b, wt);
  count_edges_i<<<3125, 256, 0, stream>>>(ei + N_EDGES, cnti);
  scan_offsets<<<1, SCAN_T, 0, stream>>>(cnti, off, cursor);
  rank_edges<<<3125, 256, 0, stream>>>(ei + N_EDGES, cursor, rank);
  edge_mlp1_mfma<<<6250, 256, 0, stream>>>(x, ei, ea, rank, wt1a, b1a, h1, stats1);
  bn_finalize<<<1, 64, 0, stream>>>(stats1, g1, be1, scsh1, 1.0f / (float)N_EDGES);
  gather_g<<<25000, 256, 0, stream>>>(h1, off, cnti, scsh1, gb);
  node_agg_mfma<<<782, 256, 0, stream>>>(gb, cnti, wt2a, b2a, mb);
  node_mlp1_mfma<<<782, 256, 0, stream>>>(x, mb, wt1b, b1b, h2, stats2);
  bn_finalize<<<1, 64, 0, stream>>>(stats2, g2, be2, scsh2, 1.0f / (float)N_NODES);
  node_mlp2_mfma<<<782, 256, 0, stream>>>(h2, wt2b, b2b, scsh2, out);
}

// Round 4
// 529.721 us; speedup vs baseline: 1.4258x; 1.4258x over previous
//
#include <hip/hip_runtime.h>
#include <hip/hip_bf16.h>
#include <cstddef>
#include <cstdint>

#define N_NODES 100000
#define N_EDGES 800000
#define EPS 1e-5f
#define SCAN_BLOCKS 98  // ceil(100000 / (256*4))

typedef __attribute__((ext_vector_type(8))) short bf16x8;
typedef __attribute__((ext_vector_type(4))) float f32x4;
typedef __attribute__((ext_vector_type(8))) unsigned short u16x8;

#define MFMA16(a, b, c) __builtin_amdgcn_mfma_f32_16x16x32_bf16(a, b, c, 0, 0, 0)

__device__ __forceinline__ unsigned short f2bf(float f) {
  return __builtin_bit_cast(unsigned short, __float2bfloat16(f));
}
__device__ __forceinline__ float bf2f(unsigned short u) {
  return __bfloat162float(__builtin_bit_cast(__hip_bfloat16, u));
}

// Load 8 consecutive fp32, convert to one bf16x8 fragment.
__device__ __forceinline__ bf16x8 cvt8(const float* __restrict__ p) {
  float4 u = *(const float4*)p;
  float4 v = *(const float4*)(p + 4);
  bf16x8 r;
  r[0] = (short)f2bf(u.x); r[1] = (short)f2bf(u.y);
  r[2] = (short)f2bf(u.z); r[3] = (short)f2bf(u.w);
  r[4] = (short)f2bf(v.x); r[5] = (short)f2bf(v.y);
  r[6] = (short)f2bf(v.z); r[7] = (short)f2bf(v.w);
  return r;
}

// ---------------------------------------------------------------------------
// Prep: transpose weights to bf16 Wt[n][k].
// Layout in wt: Wt1a[64][128] | Wt2a[64][64] | Wt1b[64][128] | Wt2b[64][64]
// ---------------------------------------------------------------------------
__global__ void prep_w(const float* __restrict__ W1a, const float* __restrict__ W2a,
                       const float* __restrict__ W1b, const float* __restrict__ W2b,
                       unsigned short* __restrict__ wt) {
  int i = blockIdx.x * 256 + threadIdx.x;
  if (i >= 24576) return;
  if (i < 8192) {
    int n = i >> 7, k = i & 127;
    wt[i] = f2bf(W1a[k * 64 + n]);
  } else if (i < 12288) {
    int j = i - 8192; int n = j >> 6, k = j & 63;
    wt[i] = f2bf(W2a[k * 64 + n]);
  } else if (i < 20480) {
    int j = i - 12288; int n = j >> 7, k = j & 127;
    wt[i] = f2bf(W1b[k * 64 + n]);
  } else {
    int j = i - 20480; int n = j >> 6, k = j & 63;
    wt[i] = f2bf(W2b[k * 64 + n]);
  }
}

// ---------------------------------------------------------------------------
// Counting sort of edges by destination node: count -> 3-phase scan -> rank.
// ---------------------------------------------------------------------------
__global__ void count_edges_i(const int* __restrict__ ei_col, int* __restrict__ cnti) {
  int e = blockIdx.x * 256 + threadIdx.x;
  if (e < N_EDGES) atomicAdd(&cnti[ei_col[e]], 1);
}

// Phase 1: per-block (1024 nodes) sums. Coalesced int4 loads, wave reduce.
__global__ __launch_bounds__(256)
void scan_p1(const int* __restrict__ cnti, int* __restrict__ bsum) {
  int t = threadIdx.x;
  int i4 = (blockIdx.x * 256 + t) * 4;
  int s = 0;
  if (i4 + 3 < N_NODES) {
    int4 v = *(const int4*)&cnti[i4];
    s = v.x + v.y + v.z + v.w;
  } else {
    for (int j = 0; j < 4; j++) if (i4 + j < N_NODES) s += cnti[i4 + j];
  }
#pragma unroll
  for (int d = 1; d < 64; d <<= 1) s += __shfl_xor(s, d);
  __shared__ int ws[4];
  if ((t & 63) == 0) ws[t >> 6] = s;
  __syncthreads();
  if (t == 0) bsum[blockIdx.x] = ws[0] + ws[1] + ws[2] + ws[3];
}

// Phase 2: exclusive scan of the 98 block sums (tiny, LDS).
__global__ __launch_bounds__(128)
void scan_p2(const int* __restrict__ bsum, int* __restrict__ bbase) {
  __shared__ int sm[SCAN_BLOCKS];
  int t = threadIdx.x;
  if (t < SCAN_BLOCKS) sm[t] = bsum[t];
  __syncthreads();
  if (t == 0) {
    int run = 0;
    for (int i = 0; i < SCAN_BLOCKS; i++) { int v = sm[i]; sm[i] = run; run += v; }
  }
  __syncthreads();
  if (t < SCAN_BLOCKS) bbase[t] = sm[t];
}

// Phase 3: intra-block exclusive scan (shfl_up + wave bases), emit off/cursor.
__global__ __launch_bounds__(256)
void scan_p3(const int* __restrict__ cnti, const int* __restrict__ bbase,
             int* __restrict__ off, int* __restrict__ cursor) {
  int t = threadIdx.x;
  int i4 = (blockIdx.x * 256 + t) * 4;
  int v0 = 0, v1 = 0, v2 = 0, v3 = 0;
  if (i4 + 3 < N_NODES) {
    int4 v = *(const int4*)&cnti[i4];
    v0 = v.x; v1 = v.y; v2 = v.z; v3 = v.w;
  } else {
    if (i4     < N_NODES) v0 = cnti[i4];
    if (i4 + 1 < N_NODES) v1 = cnti[i4 + 1];
    if (i4 + 2 < N_NODES) v2 = cnti[i4 + 2];
    if (i4 + 3 < N_NODES) v3 = cnti[i4 + 3];
  }
  int s = v0 + v1 + v2 + v3;
  int lane = t & 63, wid = t >> 6;
  int sc = s;
#pragma unroll
  for (int d = 1; d < 64; d <<= 1) {
    int n = __shfl_up(sc, d);
    if (lane >= d) sc += n;
  }
  int excl = sc - s;
  __shared__ int ws[4];
  if (lane == 63) ws[wid] = sc;
  __syncthreads();
  int wbase = 0;
#pragma unroll
  for (int i = 0; i < 4; i++) if (i < wid) wbase += ws[i];
  int base = bbase[blockIdx.x] + wbase + excl;
  if (i4 + 3 < N_NODES) {
    int4 o = make_int4(base, base + v0, base + v0 + v1, base + v0 + v1 + v2);
    *(int4*)&off[i4] = o;
    *(int4*)&cursor[i4] = o;
  } else {
    int b = base;
    if (i4     < N_NODES) { off[i4] = b; cursor[i4] = b; }     b += v0;
    if (i4 + 1 < N_NODES) { off[i4 + 1] = b; cursor[i4 + 1] = b; } b += v1;
    if (i4 + 2 < N_NODES) { off[i4 + 2] = b; cursor[i4 + 2] = b; } b += v2;
    if (i4 + 3 < N_NODES) { off[i4 + 3] = b; cursor[i4 + 3] = b; }
  }
}

// rank[e] = position of edge e in dest-sorted order.
__global__ void rank_edges(const int* __restrict__ ei_col, int* __restrict__ cursor,
                           int* __restrict__ rank) {
  int e = blockIdx.x * 256 + threadIdx.x;
  if (e < N_EDGES) {
    int c = ei_col[e];
    rank[e] = atomicAdd(&cursor[c], 1);
  }
}

// ---------------------------------------------------------------------------
// BN finalize: reduce 64 partial slots -> scale/shift per column.
// ---------------------------------------------------------------------------
__global__ void bn_finalize(const float* __restrict__ st, const float* __restrict__ g,
                            const float* __restrict__ be, float* __restrict__ scsh,
                            float inv_count) {
  int j = threadIdx.x;
  float s = 0.f, q = 0.f;
  for (int k = 0; k < 64; k++) { s += st[k * 128 + j]; q += st[k * 128 + 64 + j]; }
  float mu = s * inv_count;
  float var = q * inv_count - mu * mu;
  float sc = g[j] * rsqrtf(var + EPS);
  scsh[j] = sc;
  scsh[64 + j] = be[j] - mu * sc;
}

// ---------------------------------------------------------------------------
// Edge MLP layer 1 (K=128). Direct global->reg A-fragments, W via LDS.
// Output rows written at rank[e] (dest-sorted), so the aggregation pass
// streams. Fused BN-stat accumulation.
// ---------------------------------------------------------------------------
__global__ __launch_bounds__(256, 4)
void edge_mlp1_mfma(const float* __restrict__ x, const int* __restrict__ ei_row,
                    const float* __restrict__ ea, const int* __restrict__ rank,
                    const unsigned short* __restrict__ Wt,
                    const float* __restrict__ b1,
                    unsigned short* __restrict__ h1, float* __restrict__ stats) {
  __shared__ unsigned short Wl[64 * 136];
  __shared__ int rows[128];
  __shared__ int rankl[128];
  int tid = threadIdx.x;
  int base = blockIdx.x * 128;
  if (tid < 128) {
    rows[tid] = ei_row[base + tid];
    rankl[tid] = rank[base + tid];
  }
#pragma unroll
  for (int i = 0; i < 4; i++) {
    int g = i * 256 + tid;
    int n = g >> 4, k0 = (g & 15) * 8;
    *(u16x8*)&Wl[n * 136 + k0] = *(const u16x8*)&Wt[n * 128 + k0];
  }
  __syncthreads();

  int l = tid & 63, w = tid >> 6;
  int m16 = l & 15, g4 = l >> 4;
  int er0 = w * 32 + m16, er1 = er0 + 16;

  const float* xp0 = &x[(size_t)rows[er0] * 64 + g4 * 8];
  const float* xp1 = &x[(size_t)rows[er1] * 64 + g4 * 8];
  const float* ep0 = &ea[(size_t)(base + er0) * 64 + g4 * 8];
  const float* ep1 = &ea[(size_t)(base + er1) * 64 + g4 * 8];

  bf16x8 a[2][4];
  a[0][0] = cvt8(xp0);      a[0][1] = cvt8(xp0 + 32);
  a[1][0] = cvt8(xp1);      a[1][1] = cvt8(xp1 + 32);
  a[0][2] = cvt8(ep0);      a[0][3] = cvt8(ep0 + 32);
  a[1][2] = cvt8(ep1);      a[1][3] = cvt8(ep1 + 32);

  f32x4 acc[2][4];
#pragma unroll
  for (int nt = 0; nt < 4; nt++) {
    float bv = b1[nt * 16 + m16];
#pragma unroll
    for (int mt = 0; mt < 2; mt++) acc[mt][nt] = (f32x4){bv, bv, bv, bv};
  }
#pragma unroll
  for (int kit = 0; kit < 4; kit++) {
    bf16x8 b[4];
#pragma unroll
    for (int nt = 0; nt < 4; nt++)
      b[nt] = *(const bf16x8*)&Wl[(nt * 16 + m16) * 136 + kit * 32 + g4 * 8];
#pragma unroll
    for (int mt = 0; mt < 2; mt++)
#pragma unroll
      for (int nt = 0; nt < 4; nt++)
        acc[mt][nt] = MFMA16(a[mt][kit], b[nt], acc[mt][nt]);
  }

  float ps[4] = {0, 0, 0, 0}, pq[4] = {0, 0, 0, 0};
#pragma unroll
  for (int mt = 0; mt < 2; mt++) {
#pragma unroll
    for (int r = 0; r < 4; r++) {
      int prow = rankl[w * 32 + mt * 16 + g4 * 4 + r];
#pragma unroll
      for (int nt = 0; nt < 4; nt++) {
        float v = acc[mt][nt][r];
        h1[(size_t)prow * 64 + nt * 16 + m16] = f2bf(v);
        ps[nt] += v; pq[nt] += v * v;
      }
    }
  }
#pragma unroll
  for (int nt = 0; nt < 4; nt++) {
    ps[nt] += __shfl_xor(ps[nt], 16); ps[nt] += __shfl_xor(ps[nt], 32);
    pq[nt] += __shfl_xor(pq[nt], 16); pq[nt] += __shfl_xor(pq[nt], 32);
  }
  float ssel = (g4 == 0) ? ps[0] : (g4 == 1) ? ps[1] : (g4 == 2) ? ps[2] : ps[3];
  float qsel = (g4 == 0) ? pq[0] : (g4 == 1) ? pq[1] : (g4 == 2) ? pq[2] : pq[3];
  int slot = blockIdx.x & 63;
  atomicAdd(&stats[slot * 128 + l], ssel);
  atomicAdd(&stats[slot * 128 + 64 + l], qsel);
}

// ---------------------------------------------------------------------------
// CSR segmented mean of relu(bn(h1)) per node. h1 is dest-sorted, so each
// node's rows are contiguous: pure streaming reads, no atomics.
// One wave per node, lane = channel. Output bf16.
// ---------------------------------------------------------------------------
__global__ __launch_bounds__(256)
void gather_g(const unsigned short* __restrict__ h1, const int* __restrict__ off,
              const int* __restrict__ cnti, const float* __restrict__ scsh,
              unsigned short* __restrict__ g) {
  int w = threadIdx.x >> 6, l = threadIdx.x & 63;
  int n = blockIdx.x * 4 + w;
  if (n >= N_NODES) return;
  float sc = scsh[l], sh = scsh[64 + l];
  int o = off[n], d = cnti[n];
  float s = 0.f;
  int i = 0;
  for (; i + 2 <= d; i += 2) {
    float v0 = bf2f(h1[(size_t)(o + i) * 64 + l]);
    float v1 = bf2f(h1[(size_t)(o + i + 1) * 64 + l]);
    s += fmaxf(fmaf(v0, sc, sh), 0.f);
    s += fmaxf(fmaf(v1, sc, sh), 0.f);
  }
  if (i < d) {
    float v0 = bf2f(h1[(size_t)(o + i) * 64 + l]);
    s += fmaxf(fmaf(v0, sc, sh), 0.f);
  }
  float inv = (d > 0) ? (1.f / (float)d) : 1.f;
  g[(size_t)n * 64 + l] = f2bf(s * inv);
}

// ---------------------------------------------------------------------------
// Node-level second edge-MLP layer: m = g @ W2a + b2a for cnt>0, else 0.
// ---------------------------------------------------------------------------
__global__ __launch_bounds__(256, 4)
void node_agg_mfma(const unsigned short* __restrict__ g, const int* __restrict__ cnti,
                   const unsigned short* __restrict__ Wt2, const float* __restrict__ b2,
                   unsigned short* __restrict__ m) {
  __shared__ unsigned short Wl[64 * 72];
  int tid = threadIdx.x;
  int base = blockIdx.x * 128;
#pragma unroll
  for (int i = 0; i < 2; i++) {
    int gg = i * 256 + tid;
    int n = gg >> 3, k0 = (gg & 7) * 8;
    *(u16x8*)&Wl[n * 72 + k0] = *(const u16x8*)&Wt2[n * 64 + k0];
  }
  __syncthreads();

  int l = tid & 63, w = tid >> 6;
  int m16 = l & 15, g4 = l >> 4;
  int r0 = base + w * 32 + m16, r1 = r0 + 16;
  int c0 = (r0 < N_NODES) ? r0 : 0;
  int c1 = (r1 < N_NODES) ? r1 : 0;

  bf16x8 a[2][2];
  a[0][0] = *(const bf16x8*)&g[(size_t)c0 * 64 + g4 * 8];
  a[0][1] = *(const bf16x8*)&g[(size_t)c0 * 64 + 32 + g4 * 8];
  a[1][0] = *(const bf16x8*)&g[(size_t)c1 * 64 + g4 * 8];
  a[1][1] = *(const bf16x8*)&g[(size_t)c1 * 64 + 32 + g4 * 8];

  f32x4 acc[2][4];
#pragma unroll
  for (int nt = 0; nt < 4; nt++) {
    float bv = b2[nt * 16 + m16];
#pragma unroll
    for (int mt = 0; mt < 2; mt++) acc[mt][nt] = (f32x4){bv, bv, bv, bv};
  }
#pragma unroll
  for (int kit = 0; kit < 2; kit++) {
    bf16x8 b[4];
#pragma unroll
    for (int nt = 0; nt < 4; nt++)
      b[nt] = *(const bf16x8*)&Wl[(nt * 16 + m16) * 72 + kit * 32 + g4 * 8];
#pragma unroll
    for (int mt = 0; mt < 2; mt++)
#pragma unroll
      for (int nt = 0; nt < 4; nt++)
        acc[mt][nt] = MFMA16(a[mt][kit], b[nt], acc[mt][nt]);
  }
#pragma unroll
  for (int mt = 0; mt < 2; mt++) {
#pragma unroll
    for (int r = 0; r < 4; r++) {
      int row = base + w * 32 + mt * 16 + g4 * 4 + r;
      if (row < N_NODES) {
        bool nz = cnti[row] > 0;
#pragma unroll
        for (int nt = 0; nt < 4; nt++) {
          m[(size_t)row * 64 + nt * 16 + m16] = nz ? f2bf(acc[mt][nt][r]) : (unsigned short)0;
        }
      }
    }
  }
}

// ---------------------------------------------------------------------------
// Node MLP layer 1 (K=128): A = concat(x[n] (f32->bf16), m[n] (bf16)).
// ---------------------------------------------------------------------------
__global__ __launch_bounds__(256, 4)
void node_mlp1_mfma(const float* __restrict__ x, const unsigned short* __restrict__ m,
                    const unsigned short* __restrict__ Wt,
                    const float* __restrict__ b1,
                    unsigned short* __restrict__ h2, float* __restrict__ stats) {
  __shared__ unsigned short Wl[64 * 136];
  int tid = threadIdx.x;
  int base = blockIdx.x * 128;
#pragma unroll
  for (int i = 0; i < 4; i++) {
    int g = i * 256 + tid;
    int n = g >> 4, k0 = (g & 15) * 8;
    *(u16x8*)&Wl[n * 136 + k0] = *(const u16x8*)&Wt[n * 128 + k0];
  }
  __syncthreads();

  int l = tid & 63, w = tid >> 6;
  int m16 = l & 15, g4 = l >> 4;
  int r0 = base + w * 32 + m16, r1 = r0 + 16;
  int c0 = (r0 < N_NODES) ? r0 : 0;
  int c1 = (r1 < N_NODES) ? r1 : 0;

  const float* xp0 = &x[(size_t)c0 * 64 + g4 * 8];
  const float* xp1 = &x[(size_t)c1 * 64 + g4 * 8];

  bf16x8 a[2][4];
  a[0][0] = cvt8(xp0);      a[0][1] = cvt8(xp0 + 32);
  a[1][0] = cvt8(xp1);      a[1][1] = cvt8(xp1 + 32);
  a[0][2] = *(const bf16x8*)&m[(size_t)c0 * 64 + g4 * 8];
  a[0][3] = *(const bf16x8*)&m[(size_t)c0 * 64 + 32 + g4 * 8];
  a[1][2] = *(const bf16x8*)&m[(size_t)c1 * 64 + g4 * 8];
  a[1][3] = *(const bf16x8*)&m[(size_t)c1 * 64 + 32 + g4 * 8];

  f32x4 acc[2][4];
#pragma unroll
  for (int nt = 0; nt < 4; nt++) {
    float bv = b1[nt * 16 + m16];
#pragma unroll
    for (int mt = 0; mt < 2; mt++) acc[mt][nt] = (f32x4){bv, bv, bv, bv};
  }
#pragma unroll
  for (int kit = 0; kit < 4; kit++) {
    bf16x8 b[4];
#pragma unroll
    for (int nt = 0; nt < 4; nt++)
      b[nt] = *(const bf16x8*)&Wl[(nt * 16 + m16) * 136 + kit * 32 + g4 * 8];
#pragma unroll
    for (int mt = 0; mt < 2; mt++)
#pragma unroll
      for (int nt = 0; nt < 4; nt++)
        acc[mt][nt] = MFMA16(a[mt][kit], b[nt], acc[mt][nt]);
  }

  float ps[4] = {0, 0, 0, 0}, pq[4] = {0, 0, 0, 0};
#pragma unroll
  for (int mt = 0; mt < 2; mt++) {
    int nrow = base + w * 32 + mt * 16 + g4 * 4;
#pragma unroll
    for (int nt = 0; nt < 4; nt++) {
      int ch = nt * 16 + m16;
#pragma unroll
      for (int r = 0; r < 4; r++) {
        float v = acc[mt][nt][r];
        if (nrow + r < N_NODES) {
          h2[(size_t)(nrow + r) * 64 + ch] = f2bf(v);
          ps[nt] += v; pq[nt] += v * v;
        }
      }
    }
  }
#pragma unroll
  for (int nt = 0; nt < 4; nt++) {
    ps[nt] += __shfl_xor(ps[nt], 16); ps[nt] += __shfl_xor(ps[nt], 32);
    pq[nt] += __shfl_xor(pq[nt], 16); pq[nt] += __shfl_xor(pq[nt], 32);
  }
  float ssel = (g4 == 0) ? ps[0] : (g4 == 1) ? ps[1] : (g4 == 2) ? ps[2] : ps[3];
  float qsel = (g4 == 0) ? pq[0] : (g4 == 1) ? pq[1] : (g4 == 2) ? pq[2] : pq[3];
  int slot = blockIdx.x & 63;
  atomicAdd(&stats[slot * 128 + l], ssel);
  atomicAdd(&stats[slot * 128 + 64 + l], qsel);
}

// ---------------------------------------------------------------------------
// Node MLP layer 2 (K=64): BN+ReLU in registers; direct store. Guards.
// ---------------------------------------------------------------------------
__global__ __launch_bounds__(256, 4)
void node_mlp2_mfma(const unsigned short* __restrict__ h2, const unsigned short* __restrict__ Wt2,
                    const float* __restrict__ b2, const float* __restrict__ scsh,
                    float* __restrict__ out) {
  __shared__ unsigned short Wl[64 * 72];
  int tid = threadIdx.x;
  int base = blockIdx.x * 128;
#pragma unroll
  for (int i = 0; i < 2; i++) {
    int g = i * 256 + tid;
    int n = g >> 3, k0 = (g & 7) * 8;
    *(u16x8*)&Wl[n * 72 + k0] = *(const u16x8*)&Wt2[n * 64 + k0];
  }
  __syncthreads();

  int l = tid & 63, w = tid >> 6;
  int m16 = l & 15, g4 = l >> 4;
  int r0 = base + w * 32 + m16, r1 = r0 + 16;
  int c0 = (r0 < N_NODES) ? r0 : 0;
  int c1 = (r1 < N_NODES) ? r1 : 0;

  float sc[2][8], sh[2][8];
#pragma unroll
  for (int kit = 0; kit < 2; kit++) {
    int k = kit * 32 + g4 * 8;
    float4 s0 = *(const float4*)&scsh[k];
    float4 s1 = *(const float4*)&scsh[k + 4];
    float4 t0 = *(const float4*)&scsh[64 + k];
    float4 t1 = *(const float4*)&scsh[64 + k + 4];
    sc[kit][0] = s0.x; sc[kit][1] = s0.y; sc[kit][2] = s0.z; sc[kit][3] = s0.w;
    sc[kit][4] = s1.x; sc[kit][5] = s1.y; sc[kit][6] = s1.z; sc[kit][7] = s1.w;
    sh[kit][0] = t0.x; sh[kit][1] = t0.y; sh[kit][2] = t0.z; sh[kit][3] = t0.w;
    sh[kit][4] = t1.x; sh[kit][5] = t1.y; sh[kit][6] = t1.z; sh[kit][7] = t1.w;
  }

  bf16x8 a[2][2];
#pragma unroll
  for (int mt = 0; mt < 2; mt++) {
    const unsigned short* hp = &h2[(size_t)(mt ? c1 : c0) * 64 + g4 * 8];
#pragma unroll
    for (int kit = 0; kit < 2; kit++) {
      u16x8 hv = *(const u16x8*)(hp + kit * 32);
      bf16x8 o;
#pragma unroll
      for (int j = 0; j < 8; j++) {
        float v = fmaxf(fmaf(bf2f(hv[j]), sc[kit][j], sh[kit][j]), 0.f);
        o[j] = (short)f2bf(v);
      }
      a[mt][kit] = o;
    }
  }

  f32x4 acc[2][4];
#pragma unroll
  for (int nt = 0; nt < 4; nt++) {
    float bv = b2[nt * 16 + m16];
#pragma unroll
    for (int mt = 0; mt < 2; mt++) acc[mt][nt] = (f32x4){bv, bv, bv, bv};
  }
#pragma unroll
  for (int kit = 0; kit < 2; kit++) {
    bf16x8 b[4];
#pragma unroll
    for (int nt = 0; nt < 4; nt++)
      b[nt] = *(const bf16x8*)&Wl[(nt * 16 + m16) * 72 + kit * 32 + g4 * 8];
#pragma unroll
    for (int mt = 0; mt < 2; mt++)
#pragma unroll
      for (int nt = 0; nt < 4; nt++)
        acc[mt][nt] = MFMA16(a[mt][kit], b[nt], acc[mt][nt]);
  }
#pragma unroll
  for (int mt = 0; mt < 2; mt++) {
    int nrow = base + w * 32 + mt * 16 + g4 * 4;
#pragma unroll
    for (int nt = 0; nt < 4; nt++) {
      int ch = nt * 16 + m16;
#pragma unroll
      for (int r = 0; r < 4; r++) {
        if (nrow + r < N_NODES) out[(size_t)(nrow + r) * 64 + ch] = acc[mt][nt][r];
      }
    }
  }
}

// ---------------------------------------------------------------------------
extern "C" void kernel_launch(void* const* d_in, const int* in_sizes, int n_in,
                              void* d_out, int out_size, void* d_ws, size_t ws_size,
                              hipStream_t stream) {
  const float* x   = (const float*)d_in[0];
  const int*   ei  = (const int*)d_in[1];   // [2,E]: rows then cols
  const float* ea  = (const float*)d_in[2];
  const float* W1a = (const float*)d_in[5];
  const float* b1a = (const float*)d_in[6];
  const float* g1  = (const float*)d_in[7];
  const float* be1 = (const float*)d_in[8];
  const float* W2a = (const float*)d_in[9];
  const float* b2a = (const float*)d_in[10];
  const float* W1b = (const float*)d_in[11];
  const float* b1b = (const float*)d_in[12];
  const float* g2  = (const float*)d_in[13];
  const float* be2 = (const float*)d_in[14];
  const float* W2b = (const float*)d_in[15];
  const float* b2b = (const float*)d_in[16];
  float* out = (float*)d_out;

  // Workspace layout
  char* p = (char*)d_ws;
  unsigned short* h1 = (unsigned short*)p;  p += (size_t)N_EDGES * 64 * 2;  // 102.4 MB
  unsigned short* gb = (unsigned short*)p;  p += (size_t)N_NODES * 64 * 2;  // 12.8 MB
  unsigned short* mb = (unsigned short*)p;  p += (size_t)N_NODES * 64 * 2;  // 12.8 MB
  // --- zeroed region start ---
  int* cnti = (int*)p;                      p += (size_t)N_NODES * 4;       // 0.4 MB
  float* stats1 = (float*)p;                p += 8192 * 4;
  float* stats2 = (float*)p;                p += 8192 * 4;
  // --- zeroed region end ---
  int* off = (int*)p;                       p += (size_t)N_NODES * 4;
  int* cursor = (int*)p;                    p += (size_t)N_NODES * 4;
  int* rank = (int*)p;                      p += (size_t)N_EDGES * 4;       // 3.2 MB
  int* bsum = (int*)p;                      p += 128 * 4;
  int* bbase = (int*)p;                     p += 128 * 4;
  float* scsh1 = (float*)p;                 p += 128 * 4;
  float* scsh2 = (float*)p;                 p += 128 * 4;
  unsigned short* h2 = (unsigned short*)p;  p += (size_t)N_NODES * 64 * 2;  // 12.8 MB
  unsigned short* wt = (unsigned short*)p;  // 24576 bf16
  unsigned short* wt1a = wt;
  unsigned short* wt2a = wt + 8192;
  unsigned short* wt1b = wt + 12288;
  unsigned short* wt2b = wt + 20480;

  size_t zbytes = (size_t)N_NODES * 4 + 2 * 8192 * 4;
  (void)hipMemsetAsync(cnti, 0, zbytes, stream);

  prep_w<<<96, 256, 0, stream>>>(W1a, W2a, W1b, W2b, wt);
  count_edges_i<<<3125, 256, 0, stream>>>(ei + N_EDGES, cnti);
  scan_p1<<<SCAN_BLOCKS, 256, 0, stream>>>(cnti, bsum);
  scan_p2<<<1, 128, 0, stream>>>(bsum, bbase);
  scan_p3<<<SCAN_BLOCKS, 256, 0, stream>>>(cnti, bbase, off, cursor);
  rank_edges<<<3125, 256, 0, stream>>>(ei + N_EDGES, cursor, rank);
  edge_mlp1_mfma<<<6250, 256, 0, stream>>>(x, ei, ea, rank, wt1a, b1a, h1, stats1);
  bn_finalize<<<1, 64, 0, stream>>>(stats1, g1, be1, scsh1, 1.0f / (float)N_EDGES);
  gather_g<<<25000, 256, 0, stream>>>(h1, off, cnti, scsh1, gb);
  node_agg_mfma<<<782, 256, 0, stream>>>(gb, cnti, wt2a, b2a, mb);
  node_mlp1_mfma<<<782, 256, 0, stream>>>(x, mb, wt1b, b1b, h2, stats2);
  bn_finalize<<<1, 64, 0, stream>>>(stats2, g2, be2, scsh2, 1.0f / (float)N_NODES);
  node_mlp2_mfma<<<782, 256, 0, stream>>>(h2, wt2b, b2b, scsh2, out);
}

// Round 5
// 514.260 us; speedup vs baseline: 1.4686x; 1.0301x over previous
//
#include <hip/hip_runtime.h>
#include <hip/hip_bf16.h>
#include <cstddef>
#include <cstdint>

#define N_NODES 100000
#define N_EDGES 800000
#define EPS 1e-5f
#define SCAN_BLOCKS 98  // ceil(100000 / (256*4))

typedef __attribute__((ext_vector_type(8))) short bf16x8;
typedef __attribute__((ext_vector_type(4))) float f32x4;
typedef __attribute__((ext_vector_type(8))) unsigned short u16x8;

#define MFMA16(a, b, c) __builtin_amdgcn_mfma_f32_16x16x32_bf16(a, b, c, 0, 0, 0)

__device__ __forceinline__ unsigned short f2bf(float f) {
  return __builtin_bit_cast(unsigned short, __float2bfloat16(f));
}
__device__ __forceinline__ float bf2f(unsigned short u) {
  return __bfloat162float(__builtin_bit_cast(__hip_bfloat16, u));
}

// Load 8 consecutive fp32, convert to one bf16x8 fragment.
__device__ __forceinline__ bf16x8 cvt8(const float* __restrict__ p) {
  float4 u = *(const float4*)p;
  float4 v = *(const float4*)(p + 4);
  bf16x8 r;
  r[0] = (short)f2bf(u.x); r[1] = (short)f2bf(u.y);
  r[2] = (short)f2bf(u.z); r[3] = (short)f2bf(u.w);
  r[4] = (short)f2bf(v.x); r[5] = (short)f2bf(v.y);
  r[6] = (short)f2bf(v.z); r[7] = (short)f2bf(v.w);
  return r;
}

// ---------------------------------------------------------------------------
// Prep: transpose weights to bf16 Wt[n][k].
// Layout in wt: Wt1a[64][128] | Wt2a[64][64] | Wt1b[64][128] | Wt2b[64][64]
// ---------------------------------------------------------------------------
__global__ void prep_w(const float* __restrict__ W1a, const float* __restrict__ W2a,
                       const float* __restrict__ W1b, const float* __restrict__ W2b,
                       unsigned short* __restrict__ wt) {
  int i = blockIdx.x * 256 + threadIdx.x;
  if (i >= 24576) return;
  if (i < 8192) {
    int n = i >> 7, k = i & 127;
    wt[i] = f2bf(W1a[k * 64 + n]);
  } else if (i < 12288) {
    int j = i - 8192; int n = j >> 6, k = j & 63;
    wt[i] = f2bf(W2a[k * 64 + n]);
  } else if (i < 20480) {
    int j = i - 12288; int n = j >> 7, k = j & 127;
    wt[i] = f2bf(W1b[k * 64 + n]);
  } else {
    int j = i - 20480; int n = j >> 6, k = j & 63;
    wt[i] = f2bf(W2b[k * 64 + n]);
  }
}

// ---------------------------------------------------------------------------
// Counting sort of edges by destination node: count -> 3-phase scan -> rank.
// ---------------------------------------------------------------------------
__global__ void count_edges_i(const int* __restrict__ ei_col, int* __restrict__ cnti) {
  int e = blockIdx.x * 256 + threadIdx.x;
  if (e < N_EDGES) atomicAdd(&cnti[ei_col[e]], 1);
}

// Phase 1: per-block (1024 nodes) sums. Coalesced int4 loads, wave reduce.
__global__ __launch_bounds__(256)
void scan_p1(const int* __restrict__ cnti, int* __restrict__ bsum) {
  int t = threadIdx.x;
  int i4 = (blockIdx.x * 256 + t) * 4;
  int s = 0;
  if (i4 + 3 < N_NODES) {
    int4 v = *(const int4*)&cnti[i4];
    s = v.x + v.y + v.z + v.w;
  } else {
    for (int j = 0; j < 4; j++) if (i4 + j < N_NODES) s += cnti[i4 + j];
  }
#pragma unroll
  for (int d = 1; d < 64; d <<= 1) s += __shfl_xor(s, d);
  __shared__ int ws[4];
  if ((t & 63) == 0) ws[t >> 6] = s;
  __syncthreads();
  if (t == 0) bsum[blockIdx.x] = ws[0] + ws[1] + ws[2] + ws[3];
}

// Phase 2: exclusive scan of the 98 block sums (tiny, LDS).
__global__ __launch_bounds__(128)
void scan_p2(const int* __restrict__ bsum, int* __restrict__ bbase) {
  __shared__ int sm[SCAN_BLOCKS];
  int t = threadIdx.x;
  if (t < SCAN_BLOCKS) sm[t] = bsum[t];
  __syncthreads();
  if (t == 0) {
    int run = 0;
    for (int i = 0; i < SCAN_BLOCKS; i++) { int v = sm[i]; sm[i] = run; run += v; }
  }
  __syncthreads();
  if (t < SCAN_BLOCKS) bbase[t] = sm[t];
}

// Phase 3: intra-block exclusive scan (shfl_up + wave bases), emit off/cursor.
__global__ __launch_bounds__(256)
void scan_p3(const int* __restrict__ cnti, const int* __restrict__ bbase,
             int* __restrict__ off, int* __restrict__ cursor) {
  int t = threadIdx.x;
  int i4 = (blockIdx.x * 256 + t) * 4;
  int v0 = 0, v1 = 0, v2 = 0, v3 = 0;
  if (i4 + 3 < N_NODES) {
    int4 v = *(const int4*)&cnti[i4];
    v0 = v.x; v1 = v.y; v2 = v.z; v3 = v.w;
  } else {
    if (i4     < N_NODES) v0 = cnti[i4];
    if (i4 + 1 < N_NODES) v1 = cnti[i4 + 1];
    if (i4 + 2 < N_NODES) v2 = cnti[i4 + 2];
    if (i4 + 3 < N_NODES) v3 = cnti[i4 + 3];
  }
  int s = v0 + v1 + v2 + v3;
  int lane = t & 63, wid = t >> 6;
  int sc = s;
#pragma unroll
  for (int d = 1; d < 64; d <<= 1) {
    int n = __shfl_up(sc, d);
    if (lane >= d) sc += n;
  }
  int excl = sc - s;
  __shared__ int ws[4];
  if (lane == 63) ws[wid] = sc;
  __syncthreads();
  int wbase = 0;
#pragma unroll
  for (int i = 0; i < 4; i++) if (i < wid) wbase += ws[i];
  int base = bbase[blockIdx.x] + wbase + excl;
  if (i4 + 3 < N_NODES) {
    int4 o = make_int4(base, base + v0, base + v0 + v1, base + v0 + v1 + v2);
    *(int4*)&off[i4] = o;
    *(int4*)&cursor[i4] = o;
  } else {
    int b = base;
    if (i4     < N_NODES) { off[i4] = b; cursor[i4] = b; }     b += v0;
    if (i4 + 1 < N_NODES) { off[i4 + 1] = b; cursor[i4 + 1] = b; } b += v1;
    if (i4 + 2 < N_NODES) { off[i4 + 2] = b; cursor[i4 + 2] = b; } b += v2;
    if (i4 + 3 < N_NODES) { off[i4 + 3] = b; cursor[i4 + 3] = b; }
  }
}

// rank[e] = position of edge e in dest-sorted order.
__global__ void rank_edges(const int* __restrict__ ei_col, int* __restrict__ cursor,
                           int* __restrict__ rank) {
  int e = blockIdx.x * 256 + threadIdx.x;
  if (e < N_EDGES) {
    int c = ei_col[e];
    rank[e] = atomicAdd(&cursor[c], 1);
  }
}

// ---------------------------------------------------------------------------
// BN finalize: reduce 64 partial slots -> scale/shift per column.
// ---------------------------------------------------------------------------
__global__ void bn_finalize(const float* __restrict__ st, const float* __restrict__ g,
                            const float* __restrict__ be, float* __restrict__ scsh,
                            float inv_count) {
  int j = threadIdx.x;
  float s = 0.f, q = 0.f;
  for (int k = 0; k < 64; k++) { s += st[k * 128 + j]; q += st[k * 128 + 64 + j]; }
  float mu = s * inv_count;
  float var = q * inv_count - mu * mu;
  float sc = g[j] * rsqrtf(var + EPS);
  scsh[j] = sc;
  scsh[64 + j] = be[j] - mu * sc;
}

// ---------------------------------------------------------------------------
// Edge MLP layer 1 (K=128). Per-lane direct ei_row loads so all A-gather
// loads ISSUE before the staging barrier (they drain during it instead of
// after it). W via LDS; rank via LDS (epilogue-only). Fused BN stats.
// ---------------------------------------------------------------------------
__global__ __launch_bounds__(256, 4)
void edge_mlp1_mfma(const float* __restrict__ x, const int* __restrict__ ei_row,
                    const float* __restrict__ ea, const int* __restrict__ rank,
                    const unsigned short* __restrict__ Wt,
                    const float* __restrict__ b1,
                    unsigned short* __restrict__ h1, float* __restrict__ stats) {
  __shared__ unsigned short Wl[64 * 136];
  __shared__ int rankl[128];
  int tid = threadIdx.x;
  int base = blockIdx.x * 128;
  if (tid < 128) rankl[tid] = rank[base + tid];
#pragma unroll
  for (int i = 0; i < 4; i++) {
    int g = i * 256 + tid;
    int n = g >> 4, k0 = (g & 15) * 8;
    *(u16x8*)&Wl[n * 136 + k0] = *(const u16x8*)&Wt[n * 128 + k0];
  }

  int l = tid & 63, w = tid >> 6;
  int m16 = l & 15, g4 = l >> 4;
  int er0 = w * 32 + m16, er1 = er0 + 16;

  // Direct per-lane row loads (coalesced 64B segments); A-gather issues now.
  int row0 = ei_row[base + er0];
  int row1 = ei_row[base + er1];
  const float* xp0 = &x[(size_t)row0 * 64 + g4 * 8];
  const float* xp1 = &x[(size_t)row1 * 64 + g4 * 8];
  const float* ep0 = &ea[(size_t)(base + er0) * 64 + g4 * 8];
  const float* ep1 = &ea[(size_t)(base + er1) * 64 + g4 * 8];

  bf16x8 a[2][4];
  a[0][2] = cvt8(ep0);      a[0][3] = cvt8(ep0 + 32);
  a[1][2] = cvt8(ep1);      a[1][3] = cvt8(ep1 + 32);
  a[0][0] = cvt8(xp0);      a[0][1] = cvt8(xp0 + 32);
  a[1][0] = cvt8(xp1);      a[1][1] = cvt8(xp1 + 32);

  __syncthreads();

  f32x4 acc[2][4];
#pragma unroll
  for (int nt = 0; nt < 4; nt++) {
    float bv = b1[nt * 16 + m16];
#pragma unroll
    for (int mt = 0; mt < 2; mt++) acc[mt][nt] = (f32x4){bv, bv, bv, bv};
  }
#pragma unroll
  for (int kit = 0; kit < 4; kit++) {
    bf16x8 b[4];
#pragma unroll
    for (int nt = 0; nt < 4; nt++)
      b[nt] = *(const bf16x8*)&Wl[(nt * 16 + m16) * 136 + kit * 32 + g4 * 8];
#pragma unroll
    for (int mt = 0; mt < 2; mt++)
#pragma unroll
      for (int nt = 0; nt < 4; nt++)
        acc[mt][nt] = MFMA16(a[mt][kit], b[nt], acc[mt][nt]);
  }

  float ps[4] = {0, 0, 0, 0}, pq[4] = {0, 0, 0, 0};
#pragma unroll
  for (int mt = 0; mt < 2; mt++) {
#pragma unroll
    for (int r = 0; r < 4; r++) {
      int prow = rankl[w * 32 + mt * 16 + g4 * 4 + r];
#pragma unroll
      for (int nt = 0; nt < 4; nt++) {
        float v = acc[mt][nt][r];
        h1[(size_t)prow * 64 + nt * 16 + m16] = f2bf(v);
        ps[nt] += v; pq[nt] += v * v;
      }
    }
  }
#pragma unroll
  for (int nt = 0; nt < 4; nt++) {
    ps[nt] += __shfl_xor(ps[nt], 16); ps[nt] += __shfl_xor(ps[nt], 32);
    pq[nt] += __shfl_xor(pq[nt], 16); pq[nt] += __shfl_xor(pq[nt], 32);
  }
  float ssel = (g4 == 0) ? ps[0] : (g4 == 1) ? ps[1] : (g4 == 2) ? ps[2] : ps[3];
  float qsel = (g4 == 0) ? pq[0] : (g4 == 1) ? pq[1] : (g4 == 2) ? pq[2] : pq[3];
  int slot = blockIdx.x & 63;
  atomicAdd(&stats[slot * 128 + l], ssel);
  atomicAdd(&stats[slot * 128 + 64 + l], qsel);
}

// ---------------------------------------------------------------------------
// CSR segmented mean of relu(bn(h1)) per node. h1 is dest-sorted.
// Lane = (row-parity rp, channel-pair cp): each vector instruction reads two
// full 128B rows; 4-row unroll => 4 loads in flight. shfl_xor(32) combine,
// packed u32 stores. No atomics.
// ---------------------------------------------------------------------------
__global__ __launch_bounds__(256)
void gather_g(const unsigned short* __restrict__ h1, const int* __restrict__ off,
              const int* __restrict__ cnti, const float* __restrict__ scsh,
              unsigned short* __restrict__ g) {
  int w = threadIdx.x >> 6, l = threadIdx.x & 63;
  int n = blockIdx.x * 4 + w;
  if (n >= N_NODES) return;
  int rp = l >> 5;   // which row of a pair
  int cp = l & 31;   // channel pair: channels 2cp, 2cp+1
  float sc0 = scsh[2 * cp],      sc1 = scsh[2 * cp + 1];
  float sh0 = scsh[64 + 2 * cp], sh1 = scsh[64 + 2 * cp + 1];
  int o = off[n], d = cnti[n];
  const unsigned short* hp = h1 + (size_t)o * 64 + 2 * cp;
  float s0 = 0.f, s1 = 0.f;
  int i = rp;
  for (; i + 2 < d; i += 4) {
    uint32_t pa = *(const uint32_t*)(hp + (size_t)i * 64);
    uint32_t pb = *(const uint32_t*)(hp + (size_t)(i + 2) * 64);
    s0 += fmaxf(fmaf(bf2f((unsigned short)(pa & 0xffff)), sc0, sh0), 0.f);
    s1 += fmaxf(fmaf(bf2f((unsigned short)(pa >> 16)),    sc1, sh1), 0.f);
    s0 += fmaxf(fmaf(bf2f((unsigned short)(pb & 0xffff)), sc0, sh0), 0.f);
    s1 += fmaxf(fmaf(bf2f((unsigned short)(pb >> 16)),    sc1, sh1), 0.f);
  }
  if (i < d) {
    uint32_t pa = *(const uint32_t*)(hp + (size_t)i * 64);
    s0 += fmaxf(fmaf(bf2f((unsigned short)(pa & 0xffff)), sc0, sh0), 0.f);
    s1 += fmaxf(fmaf(bf2f((unsigned short)(pa >> 16)),    sc1, sh1), 0.f);
  }
  // combine the two row-parity halves
  s0 += __shfl_xor(s0, 32);
  s1 += __shfl_xor(s1, 32);
  if (rp == 0) {
    float inv = (d > 0) ? (1.f / (float)d) : 1.f;
    uint32_t pk = (uint32_t)f2bf(s0 * inv) | ((uint32_t)f2bf(s1 * inv) << 16);
    *(uint32_t*)&g[(size_t)n * 64 + 2 * cp] = pk;
  }
}

// ---------------------------------------------------------------------------
// Node-level second edge-MLP layer: m = g @ W2a + b2a for cnt>0, else 0.
// ---------------------------------------------------------------------------
__global__ __launch_bounds__(256, 4)
void node_agg_mfma(const unsigned short* __restrict__ g, const int* __restrict__ cnti,
                   const unsigned short* __restrict__ Wt2, const float* __restrict__ b2,
                   unsigned short* __restrict__ m) {
  __shared__ unsigned short Wl[64 * 72];
  int tid = threadIdx.x;
  int base = blockIdx.x * 128;
#pragma unroll
  for (int i = 0; i < 2; i++) {
    int gg = i * 256 + tid;
    int n = gg >> 3, k0 = (gg & 7) * 8;
    *(u16x8*)&Wl[n * 72 + k0] = *(const u16x8*)&Wt2[n * 64 + k0];
  }
  __syncthreads();

  int l = tid & 63, w = tid >> 6;
  int m16 = l & 15, g4 = l >> 4;
  int r0 = base + w * 32 + m16, r1 = r0 + 16;
  int c0 = (r0 < N_NODES) ? r0 : 0;
  int c1 = (r1 < N_NODES) ? r1 : 0;

  bf16x8 a[2][2];
  a[0][0] = *(const bf16x8*)&g[(size_t)c0 * 64 + g4 * 8];
  a[0][1] = *(const bf16x8*)&g[(size_t)c0 * 64 + 32 + g4 * 8];
  a[1][0] = *(const bf16x8*)&g[(size_t)c1 * 64 + g4 * 8];
  a[1][1] = *(const bf16x8*)&g[(size_t)c1 * 64 + 32 + g4 * 8];

  f32x4 acc[2][4];
#pragma unroll
  for (int nt = 0; nt < 4; nt++) {
    float bv = b2[nt * 16 + m16];
#pragma unroll
    for (int mt = 0; mt < 2; mt++) acc[mt][nt] = (f32x4){bv, bv, bv, bv};
  }
#pragma unroll
  for (int kit = 0; kit < 2; kit++) {
    bf16x8 b[4];
#pragma unroll
    for (int nt = 0; nt < 4; nt++)
      b[nt] = *(const bf16x8*)&Wl[(nt * 16 + m16) * 72 + kit * 32 + g4 * 8];
#pragma unroll
    for (int mt = 0; mt < 2; mt++)
#pragma unroll
      for (int nt = 0; nt < 4; nt++)
        acc[mt][nt] = MFMA16(a[mt][kit], b[nt], acc[mt][nt]);
  }
#pragma unroll
  for (int mt = 0; mt < 2; mt++) {
#pragma unroll
    for (int r = 0; r < 4; r++) {
      int row = base + w * 32 + mt * 16 + g4 * 4 + r;
      if (row < N_NODES) {
        bool nz = cnti[row] > 0;
#pragma unroll
        for (int nt = 0; nt < 4; nt++) {
          m[(size_t)row * 64 + nt * 16 + m16] = nz ? f2bf(acc[mt][nt][r]) : (unsigned short)0;
        }
      }
    }
  }
}

// ---------------------------------------------------------------------------
// Node MLP layer 1 (K=128): A = concat(x[n] (f32->bf16), m[n] (bf16)).
// ---------------------------------------------------------------------------
__global__ __launch_bounds__(256, 4)
void node_mlp1_mfma(const float* __restrict__ x, const unsigned short* __restrict__ m,
                    const unsigned short* __restrict__ Wt,
                    const float* __restrict__ b1,
                    unsigned short* __restrict__ h2, float* __restrict__ stats) {
  __shared__ unsigned short Wl[64 * 136];
  int tid = threadIdx.x;
  int base = blockIdx.x * 128;
#pragma unroll
  for (int i = 0; i < 4; i++) {
    int g = i * 256 + tid;
    int n = g >> 4, k0 = (g & 15) * 8;
    *(u16x8*)&Wl[n * 136 + k0] = *(const u16x8*)&Wt[n * 128 + k0];
  }

  int l = tid & 63, w = tid >> 6;
  int m16 = l & 15, g4 = l >> 4;
  int r0 = base + w * 32 + m16, r1 = r0 + 16;
  int c0 = (r0 < N_NODES) ? r0 : 0;
  int c1 = (r1 < N_NODES) ? r1 : 0;

  const float* xp0 = &x[(size_t)c0 * 64 + g4 * 8];
  const float* xp1 = &x[(size_t)c1 * 64 + g4 * 8];

  bf16x8 a[2][4];
  a[0][0] = cvt8(xp0);      a[0][1] = cvt8(xp0 + 32);
  a[1][0] = cvt8(xp1);      a[1][1] = cvt8(xp1 + 32);
  a[0][2] = *(const bf16x8*)&m[(size_t)c0 * 64 + g4 * 8];
  a[0][3] = *(const bf16x8*)&m[(size_t)c0 * 64 + 32 + g4 * 8];
  a[1][2] = *(const bf16x8*)&m[(size_t)c1 * 64 + g4 * 8];
  a[1][3] = *(const bf16x8*)&m[(size_t)c1 * 64 + 32 + g4 * 8];

  __syncthreads();

  f32x4 acc[2][4];
#pragma unroll
  for (int nt = 0; nt < 4; nt++) {
    float bv = b1[nt * 16 + m16];
#pragma unroll
    for (int mt = 0; mt < 2; mt++) acc[mt][nt] = (f32x4){bv, bv, bv, bv};
  }
#pragma unroll
  for (int kit = 0; kit < 4; kit++) {
    bf16x8 b[4];
#pragma unroll
    for (int nt = 0; nt < 4; nt++)
      b[nt] = *(const bf16x8*)&Wl[(nt * 16 + m16) * 136 + kit * 32 + g4 * 8];
#pragma unroll
    for (int mt = 0; mt < 2; mt++)
#pragma unroll
      for (int nt = 0; nt < 4; nt++)
        acc[mt][nt] = MFMA16(a[mt][kit], b[nt], acc[mt][nt]);
  }

  float ps[4] = {0, 0, 0, 0}, pq[4] = {0, 0, 0, 0};
#pragma unroll
  for (int mt = 0; mt < 2; mt++) {
    int nrow = base + w * 32 + mt * 16 + g4 * 4;
#pragma unroll
    for (int nt = 0; nt < 4; nt++) {
      int ch = nt * 16 + m16;
#pragma unroll
      for (int r = 0; r < 4; r++) {
        float v = acc[mt][nt][r];
        if (nrow + r < N_NODES) {
          h2[(size_t)(nrow + r) * 64 + ch] = f2bf(v);
          ps[nt] += v; pq[nt] += v * v;
        }
      }
    }
  }
#pragma unroll
  for (int nt = 0; nt < 4; nt++) {
    ps[nt] += __shfl_xor(ps[nt], 16); ps[nt] += __shfl_xor(ps[nt], 32);
    pq[nt] += __shfl_xor(pq[nt], 16); pq[nt] += __shfl_xor(pq[nt], 32);
  }
  float ssel = (g4 == 0) ? ps[0] : (g4 == 1) ? ps[1] : (g4 == 2) ? ps[2] : ps[3];
  float qsel = (g4 == 0) ? pq[0] : (g4 == 1) ? pq[1] : (g4 == 2) ? pq[2] : pq[3];
  int slot = blockIdx.x & 63;
  atomicAdd(&stats[slot * 128 + l], ssel);
  atomicAdd(&stats[slot * 128 + 64 + l], qsel);
}

// ---------------------------------------------------------------------------
// Node MLP layer 2 (K=64): BN+ReLU in registers; direct store. Guards.
// ---------------------------------------------------------------------------
__global__ __launch_bounds__(256, 4)
void node_mlp2_mfma(const unsigned short* __restrict__ h2, const unsigned short* __restrict__ Wt2,
                    const float* __restrict__ b2, const float* __restrict__ scsh,
                    float* __restrict__ out) {
  __shared__ unsigned short Wl[64 * 72];
  int tid = threadIdx.x;
  int base = blockIdx.x * 128;
#pragma unroll
  for (int i = 0; i < 2; i++) {
    int g = i * 256 + tid;
    int n = g >> 3, k0 = (g & 7) * 8;
    *(u16x8*)&Wl[n * 72 + k0] = *(const u16x8*)&Wt2[n * 64 + k0];
  }
  __syncthreads();

  int l = tid & 63, w = tid >> 6;
  int m16 = l & 15, g4 = l >> 4;
  int r0 = base + w * 32 + m16, r1 = r0 + 16;
  int c0 = (r0 < N_NODES) ? r0 : 0;
  int c1 = (r1 < N_NODES) ? r1 : 0;

  float sc[2][8], sh[2][8];
#pragma unroll
  for (int kit = 0; kit < 2; kit++) {
    int k = kit * 32 + g4 * 8;
    float4 s0 = *(const float4*)&scsh[k];
    float4 s1 = *(const float4*)&scsh[k + 4];
    float4 t0 = *(const float4*)&scsh[64 + k];
    float4 t1 = *(const float4*)&scsh[64 + k + 4];
    sc[kit][0] = s0.x; sc[kit][1] = s0.y; sc[kit][2] = s0.z; sc[kit][3] = s0.w;
    sc[kit][4] = s1.x; sc[kit][5] = s1.y; sc[kit][6] = s1.z; sc[kit][7] = s1.w;
    sh[kit][0] = t0.x; sh[kit][1] = t0.y; sh[kit][2] = t0.z; sh[kit][3] = t0.w;
    sh[kit][4] = t1.x; sh[kit][5] = t1.y; sh[kit][6] = t1.z; sh[kit][7] = t1.w;
  }

  bf16x8 a[2][2];
#pragma unroll
  for (int mt = 0; mt < 2; mt++) {
    const unsigned short* hp = &h2[(size_t)(mt ? c1 : c0) * 64 + g4 * 8];
#pragma unroll
    for (int kit = 0; kit < 2; kit++) {
      u16x8 hv = *(const u16x8*)(hp + kit * 32);
      bf16x8 o;
#pragma unroll
      for (int j = 0; j < 8; j++) {
        float v = fmaxf(fmaf(bf2f(hv[j]), sc[kit][j], sh[kit][j]), 0.f);
        o[j] = (short)f2bf(v);
      }
      a[mt][kit] = o;
    }
  }

  f32x4 acc[2][4];
#pragma unroll
  for (int nt = 0; nt < 4; nt++) {
    float bv = b2[nt * 16 + m16];
#pragma unroll
    for (int mt = 0; mt < 2; mt++) acc[mt][nt] = (f32x4){bv, bv, bv, bv};
  }
#pragma unroll
  for (int kit = 0; kit < 2; kit++) {
    bf16x8 b[4];
#pragma unroll
    for (int nt = 0; nt < 4; nt++)
      b[nt] = *(const bf16x8*)&Wl[(nt * 16 + m16) * 72 + kit * 32 + g4 * 8];
#pragma unroll
    for (int mt = 0; mt < 2; mt++)
#pragma unroll
      for (int nt = 0; nt < 4; nt++)
        acc[mt][nt] = MFMA16(a[mt][kit], b[nt], acc[mt][nt]);
  }
#pragma unroll
  for (int mt = 0; mt < 2; mt++) {
    int nrow = base + w * 32 + mt * 16 + g4 * 4;
#pragma unroll
    for (int nt = 0; nt < 4; nt++) {
      int ch = nt * 16 + m16;
#pragma unroll
      for (int r = 0; r < 4; r++) {
        if (nrow + r < N_NODES) out[(size_t)(nrow + r) * 64 + ch] = acc[mt][nt][r];
      }
    }
  }
}

// ---------------------------------------------------------------------------
extern "C" void kernel_launch(void* const* d_in, const int* in_sizes, int n_in,
                              void* d_out, int out_size, void* d_ws, size_t ws_size,
                              hipStream_t stream) {
  const float* x   = (const float*)d_in[0];
  const int*   ei  = (const int*)d_in[1];   // [2,E]: rows then cols
  const float* ea  = (const float*)d_in[2];
  const float* W1a = (const float*)d_in[5];
  const float* b1a = (const float*)d_in[6];
  const float* g1  = (const float*)d_in[7];
  const float* be1 = (const float*)d_in[8];
  const float* W2a = (const float*)d_in[9];
  const float* b2a = (const float*)d_in[10];
  const float* W1b = (const float*)d_in[11];
  const float* b1b = (const float*)d_in[12];
  const float* g2  = (const float*)d_in[13];
  const float* be2 = (const float*)d_in[14];
  const float* W2b = (const float*)d_in[15];
  const float* b2b = (const float*)d_in[16];
  float* out = (float*)d_out;

  // Workspace layout
  char* p = (char*)d_ws;
  unsigned short* h1 = (unsigned short*)p;  p += (size_t)N_EDGES * 64 * 2;  // 102.4 MB
  unsigned short* gb = (unsigned short*)p;  p += (size_t)N_NODES * 64 * 2;  // 12.8 MB
  unsigned short* mb = (unsigned short*)p;  p += (size_t)N_NODES * 64 * 2;  // 12.8 MB
  // --- zeroed region start ---
  int* cnti = (int*)p;                      p += (size_t)N_NODES * 4;       // 0.4 MB
  float* stats1 = (float*)p;                p += 8192 * 4;
  float* stats2 = (float*)p;                p += 8192 * 4;
  // --- zeroed region end ---
  int* off = (int*)p;                       p += (size_t)N_NODES * 4;
  int* cursor = (int*)p;                    p += (size_t)N_NODES * 4;
  int* rank = (int*)p;                      p += (size_t)N_EDGES * 4;       // 3.2 MB
  int* bsum = (int*)p;                      p += 128 * 4;
  int* bbase = (int*)p;                     p += 128 * 4;
  float* scsh1 = (float*)p;                 p += 128 * 4;
  float* scsh2 = (float*)p;                 p += 128 * 4;
  unsigned short* h2 = (unsigned short*)p;  p += (size_t)N_NODES * 64 * 2;  // 12.8 MB
  unsigned short* wt = (unsigned short*)p;  // 24576 bf16
  unsigned short* wt1a = wt;
  unsigned short* wt2a = wt + 8192;
  unsigned short* wt1b = wt + 12288;
  unsigned short* wt2b = wt + 20480;

  size_t zbytes = (size_t)N_NODES * 4 + 2 * 8192 * 4;
  (void)hipMemsetAsync(cnti, 0, zbytes, stream);

  prep_w<<<96, 256, 0, stream>>>(W1a, W2a, W1b, W2b, wt);
  count_edges_i<<<3125, 256, 0, stream>>>(ei + N_EDGES, cnti);
  scan_p1<<<SCAN_BLOCKS, 256, 0, stream>>>(cnti, bsum);
  scan_p2<<<1, 128, 0, stream>>>(bsum, bbase);
  scan_p3<<<SCAN_BLOCKS, 256, 0, stream>>>(cnti, bbase, off, cursor);
  rank_edges<<<3125, 256, 0, stream>>>(ei + N_EDGES, cursor, rank);
  edge_mlp1_mfma<<<6250, 256, 0, stream>>>(x, ei, ea, rank, wt1a, b1a, h1, stats1);
  bn_finalize<<<1, 64, 0, stream>>>(stats1, g1, be1, scsh1, 1.0f / (float)N_EDGES);
  gather_g<<<25000, 256, 0, stream>>>(h1, off, cnti, scsh1, gb);
  node_agg_mfma<<<782, 256, 0, stream>>>(gb, cnti, wt2a, b2a, mb);
  node_mlp1_mfma<<<782, 256, 0, stream>>>(x, mb, wt1b, b1b, h2, stats2);
  bn_finalize<<<1, 64, 0, stream>>>(stats2, g2, be2, scsh2, 1.0f / (float)N_NODES);
  node_mlp2_mfma<<<782, 256, 0, stream>>>(h2, wt2b, b2b, scsh2, out);
}